// Round 7
// baseline (472.538 us; speedup 1.0000x reference)
//
#include <hip/hip_runtime.h>

#define N_NODES 100000
#define N_EDGES 1600000
#define D 64
#define N_LAYERS 5
#define FB 1000          // fine buckets (counting sort), bucket = 100 nodes
#define BN 100           // nodes per bucket
#define NX 8             // XCD partitions of the staging array
#define BCAP_X 320       // staging capacity per (xcd,bucket) cell; mean 200,
                         // sigma ~14 -> 8.5 sigma headroom; 320*8B = 64B-mult
#define BCAP 2048        // max records per bucket in sort (mean 1600 + 11s)
#define BIN_BLOCKS 512
#define BIN_THREADS 512
#define BIN_CHUNK 3125   // 512 * 3125 = 1.6M exactly

typedef unsigned short u16;
typedef unsigned long long u64;
typedef __attribute__((ext_vector_type(8))) short bf16x8;
typedef __attribute__((ext_vector_type(4))) float f32x4;

__device__ __forceinline__ float bf2f(u16 u) {
    union { unsigned int i; float f; } v;
    v.i = ((unsigned int)u) << 16;
    return v.f;
}
__device__ __forceinline__ u16 f2bf(float f) {
    union { float f; unsigned int i; } v;
    v.f = f;
    unsigned int r = v.i + 0x7FFFu + ((v.i >> 16) & 1u);  // round-nearest-even
    return (u16)(r >> 16);
}
__device__ __forceinline__ float bf2f_lo(unsigned int pk) {
    union { unsigned int i; float f; } v;
    v.i = pk << 16;
    return v.f;
}
__device__ __forceinline__ float bf2f_hi(unsigned int pk) {
    union { unsigned int i; float f; } v;
    v.i = pk & 0xFFFF0000u;
    return v.f;
}

// ====================== CSR build via 1000-bucket counting sort ==============
// Record = u64: low32 = {(d%100)<<17 | src}, high32 = bits(ew).
// Staging partitioned into 8000 cells = (xcd = blockIdx%8) x bucket so each
// 64B line is written by ONE XCD's L2 only (round-6: WRITE 42 -> ~15MB).

__global__ __launch_bounds__(1024) void initcur_kernel(int* __restrict__ fcur)
{
    int i = blockIdx.x * 1024 + threadIdx.x;
    if (i < NX * FB) fcur[i] = i * BCAP_X;   // fixed-capacity staging cells
}

// Phase 1: bin edges into 1000 fine buckets (by dst/100), staging into this
// block's XCD partition. dst read plain (12.5KB chunk -> pass-2 re-read hits
// L1); src/ew read once, nt (zero reuse); staging stores plain (L2 merge).
__global__ __launch_bounds__(BIN_THREADS) void bin_kernel(
    const int* __restrict__ src, const int* __restrict__ dst,
    const float* __restrict__ ew, int* __restrict__ fcur,
    u64* __restrict__ stag)
{
    __shared__ int hc[FB];
    const int xbase = (blockIdx.x & (NX - 1)) * FB;   // this XCD's cell row
    for (int b = threadIdx.x; b < FB; b += BIN_THREADS) hc[b] = 0;
    __syncthreads();
    const int e0 = blockIdx.x * BIN_CHUNK;
    for (int e = e0 + threadIdx.x; e < e0 + BIN_CHUNK; e += BIN_THREADS) {
        int d = dst[e];
        atomicAdd(&hc[d / BN], 1);
    }
    __syncthreads();
    for (int b = threadIdx.x; b < FB; b += BIN_THREADS) {
        int c = hc[b];
        if (c) hc[b] = atomicAdd(&fcur[xbase + b], c);  // -> global cursor
    }
    __syncthreads();
    for (int e = e0 + threadIdx.x; e < e0 + BIN_CHUNK; e += BIN_THREADS) {
        int d = dst[e];                           // L1-resident re-read
        int b = d / BN;
        int pos = atomicAdd(&hc[b], 1);           // LDS atomic -> global slot
        int s   = __builtin_nontemporal_load(&src[e]);
        float w = __builtin_nontemporal_load(&ew[e]);
        unsigned int pk = (unsigned int)((d - b * BN) << 17) | (unsigned int)s;
        u64 rec = ((u64)(unsigned int)__float_as_int(w) << 32) | pk;
        stag[pos] = rec;                          // plain: L2 write-merge
    }
}

// Exclusive scan of bucket sizes (summing the 8 XCD cells per bucket) ->
// fbase = CSR base per bucket (bucket order == node order).
__global__ __launch_bounds__(1024) void fscan_kernel(
    const int* __restrict__ fcur, int* __restrict__ fbase,
    int* __restrict__ rowptr)
{
    __shared__ int s[1024];
    int t = threadIdx.x;
    int v = 0;
    if (t < FB) {
        #pragma unroll
        for (int x = 0; x < NX; ++x) {
            int cell = x * FB + t;
            v += fcur[cell] - cell * BCAP_X;      // cell size
        }
    }
    s[t] = v;
    __syncthreads();
    for (int off = 1; off < 1024; off <<= 1) {
        int u = (t >= off) ? s[t - off] : 0;
        __syncthreads();
        s[t] += u;
        __syncthreads();
    }
    if (t < FB) fbase[t] = s[t] - v;
    if (t == FB - 1) {
        fbase[FB] = s[t];
        rowptr[N_NODES] = s[t];
    }
}

// Phase 2: one block per bucket. Stream the bucket's 8 XCD sub-segments into
// LDS + 100-counter histogram; tiny scan -> per-node rowptr AND local ranks;
// scatter into the bucket's contiguous ~12.8KB CSR slice (one block = one
// XCD = full-sector writebacks). No global atomics at all.
__global__ __launch_bounds__(256) void sort_kernel(
    const u64* __restrict__ stag, const int* __restrict__ fcur,
    const int* __restrict__ fbase, int* __restrict__ rowptr,
    int2* __restrict__ edges)
{
    __shared__ u64 ls[BCAP];       // 16 KB segment cache
    __shared__ int cnt[BN];
    __shared__ int cur[BN];
    __shared__ int sc[128];
    const int b = blockIdx.x;
    const int base = fbase[b];
    const int t = threadIdx.x;
    for (int i = t; i < BN; i += 256) cnt[i] = 0;
    __syncthreads();
    int ofs = 0;
    #pragma unroll
    for (int x = 0; x < NX; ++x) {
        int cell = x * FB + b;
        int sz = fcur[cell] - cell * BCAP_X;      // uniform scalar load
        const u64* sp = stag + (size_t)cell * BCAP_X;
        for (int i = t; i < sz; i += 256) {
            u64 r = __builtin_nontemporal_load(&sp[i]);
            ls[ofs + i] = r;
            atomicAdd(&cnt[((unsigned int)r) >> 17], 1);
        }
        ofs += sz;
    }
    const int size = ofs;
    __syncthreads();
    if (t < 128) sc[t] = (t < BN) ? cnt[t] : 0;
    __syncthreads();
    for (int off = 1; off < 128; off <<= 1) {
        int u = 0;
        if (t < 128 && t >= off) u = sc[t - off];
        __syncthreads();
        if (t < 128) sc[t] += u;
        __syncthreads();
    }
    if (t < BN) {
        int excl = sc[t] - cnt[t];
        rowptr[b * BN + t] = base + excl;
        cur[t] = excl;
    }
    __syncthreads();
    for (int i = t; i < size; i += 256) {
        u64 r = ls[i];
        unsigned int lo = (unsigned int)r;
        int dloc = lo >> 17;
        int rank = atomicAdd(&cur[dloc], 1);
        edges[base + rank] = make_int2((int)(lo & 0x1FFFFu),
                                       (int)(unsigned int)(r >> 32));
    }
}

// ======================= f32 -> bf16 convert (input x) =======================
__global__ __launch_bounds__(256) void f2bf_kernel(
    const float* __restrict__ in, u16* __restrict__ out)
{
    int i = blockIdx.x * 256 + threadIdx.x;   // one float4 per thread
    if (i >= (N_NODES * D) / 4) return;
    float4 v = ((const float4*)in)[i];
    ushort4 o;
    o.x = f2bf(v.x); o.y = f2bf(v.y); o.z = f2bf(v.z); o.w = f2bf(v.w);
    ((ushort4*)out)[i] = o;
}

// ================== Weight prep: W2T[l][n][k] bf16, k = [Wrel;Wroot] =========
__global__ __launch_bounds__(256) void wprep_kernel(
    const float* __restrict__ Wrel, const float* __restrict__ Wroot,
    u16* __restrict__ W2T)
{
    int i = blockIdx.x * 256 + threadIdx.x;  // over 5*64*128
    if (i >= N_LAYERS * 64 * 128) return;
    int l = i / (64 * 128);
    int rem = i % (64 * 128);
    int n = rem >> 7;   // out dim
    int k = rem & 127;  // input dim (0..63 = rel/agg, 64..127 = root/x)
    float v = (k < 64) ? Wrel[l * 4096 + k * 64 + n]
                       : Wroot[l * 4096 + (k - 64) * 64 + n];
    W2T[i] = f2bf(v);
}

// ================= Fused layer: aggregate (gather) + MFMA update =============
// Wave owns 16 nodes = the MFMA A-tile. Phase A: the proven 2-node/32-lane
// bf16x2-dword gather, 8 sub-phases, results written to a wave-private 2KB
// LDS tile instead of global (kills the agg->HBM->update 25.6MB round-trip
// per layer + one launch). Rows XOR-swizzled (byte ^= (row&7)<<4): the
// phase-B column read of a [16][128B] row-major tile is otherwise a 16-way
// bank conflict (guide G4). Same wave produces & consumes -> no barrier.
// hin/hout ping-pong: other blocks gather from ALL of hin, so in-place
// update is a cross-block race; write goes to the other buffer.
__global__ __launch_bounds__(256) void layer_kernel(
    const u16* __restrict__ hin, const int* __restrict__ rowptr,
    const int2* __restrict__ edges, const u16* __restrict__ W2T,
    const float* __restrict__ brel,
    u16* __restrict__ hout_bf, float* __restrict__ hout_f32, int relu)
{
    __shared__ u16 aggs[4][16][64];   // 8KB: per-wave [node][dim] swizzled
    const int wave = threadIdx.x >> 6;
    const int lane = threadIdx.x & 63;
    const int nb16 = blockIdx.x * 64 + wave * 16;
    const int sl   = lane & 31;       // sublane: dim pair -> dims 2sl, 2sl+1
    const int half = lane >> 5;
    u16* wtile = &aggs[wave][0][0];

    // ---- Phase A: aggregate 16 nodes, 2 per sub-phase ----
    for (int t = 0; t < 8; ++t) {
        int nl = 2 * t + half;            // node-local 0..15
        int node = nb16 + nl;
        float acc0 = 0.f, acc1 = 0.f;
        if (node < N_NODES) {
            int b = rowptr[node];
            int e = rowptr[node + 1];
            for (int base = b; base < e; base += 32) {
                int cnt = min(32, e - base);
                int idx = 0;
                float wv = 0.f;
                if (sl < cnt) {
                    int2 p = edges[base + sl];   // per-half coalesced 256B
                    idx = p.x;
                    wv = __int_as_float(p.y);
                }
                int j = 0;
                for (; j + 8 <= cnt; j += 8) {
                    int s0 = __shfl(idx, j + 0, 32), s1 = __shfl(idx, j + 1, 32);
                    int s2 = __shfl(idx, j + 2, 32), s3 = __shfl(idx, j + 3, 32);
                    int s4 = __shfl(idx, j + 4, 32), s5 = __shfl(idx, j + 5, 32);
                    int s6 = __shfl(idx, j + 6, 32), s7 = __shfl(idx, j + 7, 32);
                    float w0 = __shfl(wv, j + 0, 32), w1 = __shfl(wv, j + 1, 32);
                    float w2 = __shfl(wv, j + 2, 32), w3 = __shfl(wv, j + 3, 32);
                    float w4 = __shfl(wv, j + 4, 32), w5 = __shfl(wv, j + 5, 32);
                    float w6 = __shfl(wv, j + 6, 32), w7 = __shfl(wv, j + 7, 32);
                    unsigned int p0 = *(const unsigned int*)(hin + ((size_t)s0 << 6) + sl * 2);
                    unsigned int p1 = *(const unsigned int*)(hin + ((size_t)s1 << 6) + sl * 2);
                    unsigned int p2 = *(const unsigned int*)(hin + ((size_t)s2 << 6) + sl * 2);
                    unsigned int p3 = *(const unsigned int*)(hin + ((size_t)s3 << 6) + sl * 2);
                    unsigned int p4 = *(const unsigned int*)(hin + ((size_t)s4 << 6) + sl * 2);
                    unsigned int p5 = *(const unsigned int*)(hin + ((size_t)s5 << 6) + sl * 2);
                    unsigned int p6 = *(const unsigned int*)(hin + ((size_t)s6 << 6) + sl * 2);
                    unsigned int p7 = *(const unsigned int*)(hin + ((size_t)s7 << 6) + sl * 2);
                    acc0 += bf2f_lo(p0) * w0 + bf2f_lo(p1) * w1
                          + bf2f_lo(p2) * w2 + bf2f_lo(p3) * w3
                          + bf2f_lo(p4) * w4 + bf2f_lo(p5) * w5
                          + bf2f_lo(p6) * w6 + bf2f_lo(p7) * w7;
                    acc1 += bf2f_hi(p0) * w0 + bf2f_hi(p1) * w1
                          + bf2f_hi(p2) * w2 + bf2f_hi(p3) * w3
                          + bf2f_hi(p4) * w4 + bf2f_hi(p5) * w5
                          + bf2f_hi(p6) * w6 + bf2f_hi(p7) * w7;
                }
                for (; j < cnt; ++j) {
                    int s = __shfl(idx, j, 32);
                    float w = __shfl(wv, j, 32);
                    unsigned int pk = *(const unsigned int*)(hin + ((size_t)s << 6) + sl * 2);
                    acc0 += bf2f_lo(pk) * w;
                    acc1 += bf2f_hi(pk) * w;
                }
            }
        }
        // dims (2sl, 2sl+1) of row nl, XOR-swizzled within the row
        int u16idx = (nl << 6) | ((sl * 2) ^ ((nl & 7) << 3));
        unsigned int o = ((unsigned int)f2bf(acc1) << 16) | f2bf(acc0);
        *(unsigned int*)(wtile + u16idx) = o;
    }

    // ---- Phase B: A = [agg ; hin_own] @ W2T + b (16x16x32 MFMA x16) ----
    const int m = lane & 15;   // node-in-tile for A; out-dim-in-tile for B/D
    const int q = lane >> 4;   // quad

    bf16x8 a[4];
    {
        int r0 = (m << 6) | ((q * 8) ^ ((m & 7) << 3));        // dims 8q..
        int r1 = (m << 6) | ((32 + q * 8) ^ ((m & 7) << 3));   // dims 32+8q..
        a[0] = *(const bf16x8*)(wtile + r0);   // k  0..31 (agg)
        a[1] = *(const bf16x8*)(wtile + r1);   // k 32..63 (agg)
    }
    int anode = nb16 + m;
    size_t rowa = (size_t)((anode < N_NODES) ? anode : 0) << 6;
    a[2] = *(const bf16x8*)(hin + rowa + q * 8);        // k 64..95 (x)
    a[3] = *(const bf16x8*)(hin + rowa + 32 + q * 8);   // k 96..127 (x)

    bf16x8 bfr[4][4];  // [ntile][kstep]
    #pragma unroll
    for (int nt = 0; nt < 4; ++nt)
        #pragma unroll
        for (int kk = 0; kk < 4; ++kk)
            bfr[nt][kk] = *(const bf16x8*)(W2T + (size_t)(nt * 16 + m) * 128
                                           + kk * 32 + q * 8);

    f32x4 acc[4];
    #pragma unroll
    for (int nt = 0; nt < 4; ++nt) {
        float bv = brel[nt * 16 + m];
        acc[nt] = (f32x4){bv, bv, bv, bv};
    }

    #pragma unroll
    for (int kk = 0; kk < 4; ++kk)
        #pragma unroll
        for (int nt = 0; nt < 4; ++nt)
            acc[nt] = __builtin_amdgcn_mfma_f32_16x16x32_bf16(
                a[kk], bfr[nt][kk], acc[nt], 0, 0, 0);

    #pragma unroll
    for (int nt = 0; nt < 4; ++nt)
        #pragma unroll
        for (int r = 0; r < 4; ++r) {
            int n2 = nb16 + q * 4 + r;           // node (row of D)
            if (n2 < N_NODES) {
                float v = acc[nt][r];
                if (relu) v = fmaxf(v, 0.f);
                int dim = nt * 16 + m;           // out dim (col of D)
                if (hout_f32) hout_f32[(size_t)n2 * 64 + dim] = v;
                else          hout_bf [(size_t)n2 * 64 + dim] = f2bf(v);
            }
        }
}

extern "C" void kernel_launch(void* const* d_in, const int* in_sizes, int n_in,
                              void* d_out, int out_size, void* d_ws, size_t ws_size,
                              hipStream_t stream)
{
    const float* x     = (const float*)d_in[0];
    const int*   ei    = (const int*)d_in[1];   // [2, E] int32
    const float* ew    = (const float*)d_in[2];
    const float* Wrel  = (const float*)d_in[3]; // [5, 64, 64]
    const float* brel  = (const float*)d_in[4]; // [5, 64]
    const float* Wroot = (const float*)d_in[5]; // [5, 64, 64]
    float* out = (float*)d_out;

    const int* src = ei;
    const int* dst = ei + N_EDGES;

    const size_t featb_bytes = (size_t)N_NODES * D * 2;  // 12.8 MB bf16
    char* ws = (char*)d_ws;
    size_t off = 0;
    u16*  hb     = (u16*)(ws + off);  off += featb_bytes;   // ping
    u16*  hb2    = (u16*)(ws + off);  off += featb_bytes;   // pong
    u16*  W2T    = (u16*)(ws + off);  off += (size_t)N_LAYERS * 64 * 128 * 2;
    int*  rowptr = (int*)(ws + off);  off += 400016;
    int*  fcur   = (int*)(ws + off);  off += NX * FB * 4;
    int*  fbase  = (int*)(ws + off);  off += (FB + 1) * 4 + 60;
    int2* edges  = (int2*)(ws + off); off += (size_t)N_EDGES * 8;

    // stag aliases hb+hb2 (8000 cells * 320 * 8B = 20.48MB < 25.6MB): live
    // only bin -> sort, both complete (stream-ordered) before f2bf writes hb.
    u64* stag = (u64*)ws;

    u16* hbuf[2] = {hb, hb2};

    const int cblocks = (N_NODES * D / 4 + 255) / 256;
    const int wblocks = (N_LAYERS * 64 * 128 + 255) / 256;  // 160
    const int lblocks = (N_NODES + 63) / 64;         // 1563 (64 nodes/block)

    // ---- CSR build (counting sort) + converts ----
    initcur_kernel<<<8, 1024, 0, stream>>>(fcur);
    bin_kernel<<<BIN_BLOCKS, BIN_THREADS, 0, stream>>>(src, dst, ew, fcur, stag);
    fscan_kernel<<<1, 1024, 0, stream>>>(fcur, fbase, rowptr);
    sort_kernel<<<FB, 256, 0, stream>>>(stag, fcur, fbase, rowptr, edges);
    f2bf_kernel<<<cblocks, 256, 0, stream>>>(x, hb);
    wprep_kernel<<<wblocks, 256, 0, stream>>>(Wrel, Wroot, W2T);

    // ---- 5 fused GraphConv layers (ping-pong h buffers) ----
    for (int layer = 0; layer < N_LAYERS; ++layer) {
        int last = (layer == N_LAYERS - 1);
        layer_kernel<<<lblocks, 256, 0, stream>>>(
            hbuf[layer & 1], rowptr, edges,
            W2T + (size_t)layer * 64 * 128,
            brel + (size_t)layer * D,
            last ? nullptr : hbuf[(layer + 1) & 1],
            last ? out : nullptr,
            last ? 0 : 1);
    }
}

// Round 8
// 397.169 us; speedup vs baseline: 1.1898x; 1.1898x over previous
//
#include <hip/hip_runtime.h>

#define N_NODES 100000
#define N_EDGES 1600000
#define D 64
#define N_LAYERS 5
#define FB 1000          // fine buckets (counting sort), bucket = 100 nodes
#define BN 100           // nodes per bucket
#define NX 8             // XCD partitions of the staging array
#define BCAP_X 320       // staging capacity per (xcd,bucket) cell; mean 200,
                         // sigma ~14 -> 8.5 sigma headroom; 320*8B = 64B-mult
#define BCAP 2048        // max records per bucket in sort (mean 1600 + 11s)
#define BIN_BLOCKS 512
#define BIN_THREADS 512
#define BIN_CHUNK 3125   // 512 * 3125 = 1.6M exactly

typedef unsigned short u16;
typedef unsigned long long u64;
typedef __attribute__((ext_vector_type(8))) short bf16x8;
typedef __attribute__((ext_vector_type(4))) float f32x4;

__device__ __forceinline__ float bf2f(u16 u) {
    union { unsigned int i; float f; } v;
    v.i = ((unsigned int)u) << 16;
    return v.f;
}
__device__ __forceinline__ u16 f2bf(float f) {
    union { float f; unsigned int i; } v;
    v.f = f;
    unsigned int r = v.i + 0x7FFFu + ((v.i >> 16) & 1u);  // round-nearest-even
    return (u16)(r >> 16);
}
__device__ __forceinline__ float bf2f_lo(unsigned int pk) {
    union { unsigned int i; float f; } v;
    v.i = pk << 16;
    return v.f;
}
__device__ __forceinline__ float bf2f_hi(unsigned int pk) {
    union { unsigned int i; float f; } v;
    v.i = pk & 0xFFFF0000u;
    return v.f;
}

// ====================== CSR build via 1000-bucket counting sort ==============
// Record = u64: low32 = {(d%100)<<17 | src}, high32 = bits(ew).
// Staging partitioned into 8000 cells = (xcd = blockIdx%8) x bucket so each
// 64B line is written by ONE XCD's L2 only (round-6: WRITE 42 -> ~15MB).

__global__ __launch_bounds__(1024) void initcur_kernel(int* __restrict__ fcur)
{
    int i = blockIdx.x * 1024 + threadIdx.x;
    if (i < NX * FB) fcur[i] = i * BCAP_X;   // fixed-capacity staging cells
}

// Phase 1: bin edges into 1000 fine buckets (by dst/100), staging into this
// block's XCD partition. dst read plain (12.5KB chunk -> pass-2 re-read hits
// L1); src/ew read once, nt (zero reuse); staging stores plain (L2 merge).
__global__ __launch_bounds__(BIN_THREADS) void bin_kernel(
    const int* __restrict__ src, const int* __restrict__ dst,
    const float* __restrict__ ew, int* __restrict__ fcur,
    u64* __restrict__ stag)
{
    __shared__ int hc[FB];
    const int xbase = (blockIdx.x & (NX - 1)) * FB;   // this XCD's cell row
    for (int b = threadIdx.x; b < FB; b += BIN_THREADS) hc[b] = 0;
    __syncthreads();
    const int e0 = blockIdx.x * BIN_CHUNK;
    for (int e = e0 + threadIdx.x; e < e0 + BIN_CHUNK; e += BIN_THREADS) {
        int d = dst[e];
        atomicAdd(&hc[d / BN], 1);
    }
    __syncthreads();
    for (int b = threadIdx.x; b < FB; b += BIN_THREADS) {
        int c = hc[b];
        if (c) hc[b] = atomicAdd(&fcur[xbase + b], c);  // -> global cursor
    }
    __syncthreads();
    for (int e = e0 + threadIdx.x; e < e0 + BIN_CHUNK; e += BIN_THREADS) {
        int d = dst[e];                           // L1-resident re-read
        int b = d / BN;
        int pos = atomicAdd(&hc[b], 1);           // LDS atomic -> global slot
        int s   = __builtin_nontemporal_load(&src[e]);
        float w = __builtin_nontemporal_load(&ew[e]);
        unsigned int pk = (unsigned int)((d - b * BN) << 17) | (unsigned int)s;
        u64 rec = ((u64)(unsigned int)__float_as_int(w) << 32) | pk;
        stag[pos] = rec;                          // plain: L2 write-merge
    }
}

// Exclusive scan of bucket sizes (summing the 8 XCD cells per bucket) ->
// fbase = CSR base per bucket (bucket order == node order).
__global__ __launch_bounds__(1024) void fscan_kernel(
    const int* __restrict__ fcur, int* __restrict__ fbase,
    int* __restrict__ rowptr)
{
    __shared__ int s[1024];
    int t = threadIdx.x;
    int v = 0;
    if (t < FB) {
        #pragma unroll
        for (int x = 0; x < NX; ++x) {
            int cell = x * FB + t;
            v += fcur[cell] - cell * BCAP_X;      // cell size
        }
    }
    s[t] = v;
    __syncthreads();
    for (int off = 1; off < 1024; off <<= 1) {
        int u = (t >= off) ? s[t - off] : 0;
        __syncthreads();
        s[t] += u;
        __syncthreads();
    }
    if (t < FB) fbase[t] = s[t] - v;
    if (t == FB - 1) {
        fbase[FB] = s[t];
        rowptr[N_NODES] = s[t];
    }
}

// Phase 2: one block per bucket. Stream the bucket's 8 XCD sub-segments into
// LDS + 100-counter histogram; tiny scan -> per-node rowptr AND local ranks;
// scatter into the bucket's contiguous ~12.8KB CSR slice (one block = one
// XCD = full-sector writebacks). No global atomics at all.
__global__ __launch_bounds__(256) void sort_kernel(
    const u64* __restrict__ stag, const int* __restrict__ fcur,
    const int* __restrict__ fbase, int* __restrict__ rowptr,
    int2* __restrict__ edges)
{
    __shared__ u64 ls[BCAP];       // 16 KB segment cache
    __shared__ int cnt[BN];
    __shared__ int cur[BN];
    __shared__ int sc[128];
    const int b = blockIdx.x;
    const int base = fbase[b];
    const int t = threadIdx.x;
    for (int i = t; i < BN; i += 256) cnt[i] = 0;
    __syncthreads();
    int ofs = 0;
    #pragma unroll
    for (int x = 0; x < NX; ++x) {
        int cell = x * FB + b;
        int sz = fcur[cell] - cell * BCAP_X;      // uniform scalar load
        const u64* sp = stag + (size_t)cell * BCAP_X;
        for (int i = t; i < sz; i += 256) {
            u64 r = __builtin_nontemporal_load(&sp[i]);
            ls[ofs + i] = r;
            atomicAdd(&cnt[((unsigned int)r) >> 17], 1);
        }
        ofs += sz;
    }
    const int size = ofs;
    __syncthreads();
    if (t < 128) sc[t] = (t < BN) ? cnt[t] : 0;
    __syncthreads();
    for (int off = 1; off < 128; off <<= 1) {
        int u = 0;
        if (t < 128 && t >= off) u = sc[t - off];
        __syncthreads();
        if (t < 128) sc[t] += u;
        __syncthreads();
    }
    if (t < BN) {
        int excl = sc[t] - cnt[t];
        rowptr[b * BN + t] = base + excl;
        cur[t] = excl;
    }
    __syncthreads();
    for (int i = t; i < size; i += 256) {
        u64 r = ls[i];
        unsigned int lo = (unsigned int)r;
        int dloc = lo >> 17;
        int rank = atomicAdd(&cur[dloc], 1);
        edges[base + rank] = make_int2((int)(lo & 0x1FFFFu),
                                       (int)(unsigned int)(r >> 32));
    }
}

// ======================= f32 -> bf16 convert (input x) =======================
__global__ __launch_bounds__(256) void f2bf_kernel(
    const float* __restrict__ in, u16* __restrict__ out)
{
    int i = blockIdx.x * 256 + threadIdx.x;   // one float4 per thread
    if (i >= (N_NODES * D) / 4) return;
    float4 v = ((const float4*)in)[i];
    ushort4 o;
    o.x = f2bf(v.x); o.y = f2bf(v.y); o.z = f2bf(v.z); o.w = f2bf(v.w);
    ((ushort4*)out)[i] = o;
}

// ================== Weight prep: W2T[l][n][k] bf16, k = [Wrel;Wroot] =========
__global__ __launch_bounds__(256) void wprep_kernel(
    const float* __restrict__ Wrel, const float* __restrict__ Wroot,
    u16* __restrict__ W2T)
{
    int i = blockIdx.x * 256 + threadIdx.x;  // over 5*64*128
    if (i >= N_LAYERS * 64 * 128) return;
    int l = i / (64 * 128);
    int rem = i % (64 * 128);
    int n = rem >> 7;   // out dim
    int k = rem & 127;  // input dim (0..63 = rel/agg, 64..127 = root/x)
    float v = (k < 64) ? Wrel[l * 4096 + k * 64 + n]
                       : Wroot[l * 4096 + (k - 64) * 64 + n];
    W2T[i] = f2bf(v);
}

// ================= Fused layer v2: high-TLP gather + MFMA update =============
// Round-7 lesson: fusing at 16 nodes/WAVE cut gather TLP 8x (6252 waves vs
// the split agg kernel's 50000) and the latency-bound gather regressed 41 ->
// 70us. v2 keeps the fusion but restores TLP: block = 512 threads = 8 waves
// = 16 nodes (one MFMA A-tile; 6250 x 16 = 100000 exactly, no tail). Phase
// A: each wave gathers TWO nodes (identical code+swizzle to round 7, HW-
// verified) into the block's 2KB LDS tile -> 50000 independent gather waves.
// One barrier. Phase B: waves 0-3 each take one n-tile (4 MFMAs) + store.
// Keeps fusion wins (no agg HBM round-trip, half the launches). hin/hout
// ping-pong: other blocks gather from ALL of hin -> in-place is a race.
__global__ __launch_bounds__(512) void layer_kernel(
    const u16* __restrict__ hin, const int* __restrict__ rowptr,
    const int2* __restrict__ edges, const u16* __restrict__ W2T,
    const float* __restrict__ brel,
    u16* __restrict__ hout_bf, float* __restrict__ hout_f32, int relu)
{
    __shared__ u16 aggs[16][64];      // 2KB [node][dim], rows XOR-swizzled
    const int wave = threadIdx.x >> 6;
    const int lane = threadIdx.x & 63;
    const int nb16 = blockIdx.x * 16;
    const int sl   = lane & 31;       // sublane: dim pair -> dims 2sl, 2sl+1
    const int half = lane >> 5;

    // ---- Phase A: this wave aggregates nodes nb16+2*wave, nb16+2*wave+1 ----
    {
        int nl = 2 * wave + half;         // node-local 0..15 (exact fit)
        int node = nb16 + nl;
        float acc0 = 0.f, acc1 = 0.f;
        int b = rowptr[node];
        int e = rowptr[node + 1];
        for (int base = b; base < e; base += 32) {
            int cnt = min(32, e - base);
            int idx = 0;
            float wv = 0.f;
            if (sl < cnt) {
                int2 p = edges[base + sl];   // per-half coalesced 256B
                idx = p.x;
                wv = __int_as_float(p.y);
            }
            int j = 0;
            for (; j + 8 <= cnt; j += 8) {
                int s0 = __shfl(idx, j + 0, 32), s1 = __shfl(idx, j + 1, 32);
                int s2 = __shfl(idx, j + 2, 32), s3 = __shfl(idx, j + 3, 32);
                int s4 = __shfl(idx, j + 4, 32), s5 = __shfl(idx, j + 5, 32);
                int s6 = __shfl(idx, j + 6, 32), s7 = __shfl(idx, j + 7, 32);
                float w0 = __shfl(wv, j + 0, 32), w1 = __shfl(wv, j + 1, 32);
                float w2 = __shfl(wv, j + 2, 32), w3 = __shfl(wv, j + 3, 32);
                float w4 = __shfl(wv, j + 4, 32), w5 = __shfl(wv, j + 5, 32);
                float w6 = __shfl(wv, j + 6, 32), w7 = __shfl(wv, j + 7, 32);
                unsigned int p0 = *(const unsigned int*)(hin + ((size_t)s0 << 6) + sl * 2);
                unsigned int p1 = *(const unsigned int*)(hin + ((size_t)s1 << 6) + sl * 2);
                unsigned int p2 = *(const unsigned int*)(hin + ((size_t)s2 << 6) + sl * 2);
                unsigned int p3 = *(const unsigned int*)(hin + ((size_t)s3 << 6) + sl * 2);
                unsigned int p4 = *(const unsigned int*)(hin + ((size_t)s4 << 6) + sl * 2);
                unsigned int p5 = *(const unsigned int*)(hin + ((size_t)s5 << 6) + sl * 2);
                unsigned int p6 = *(const unsigned int*)(hin + ((size_t)s6 << 6) + sl * 2);
                unsigned int p7 = *(const unsigned int*)(hin + ((size_t)s7 << 6) + sl * 2);
                acc0 += bf2f_lo(p0) * w0 + bf2f_lo(p1) * w1
                      + bf2f_lo(p2) * w2 + bf2f_lo(p3) * w3
                      + bf2f_lo(p4) * w4 + bf2f_lo(p5) * w5
                      + bf2f_lo(p6) * w6 + bf2f_lo(p7) * w7;
                acc1 += bf2f_hi(p0) * w0 + bf2f_hi(p1) * w1
                      + bf2f_hi(p2) * w2 + bf2f_hi(p3) * w3
                      + bf2f_hi(p4) * w4 + bf2f_hi(p5) * w5
                      + bf2f_hi(p6) * w6 + bf2f_hi(p7) * w7;
            }
            for (; j < cnt; ++j) {
                int s = __shfl(idx, j, 32);
                float w = __shfl(wv, j, 32);
                unsigned int pk = *(const unsigned int*)(hin + ((size_t)s << 6) + sl * 2);
                acc0 += bf2f_lo(pk) * w;
                acc1 += bf2f_hi(pk) * w;
            }
        }
        // dims (2sl, 2sl+1) of row nl, XOR-swizzled within the row
        int u16idx = (nl << 6) | ((sl * 2) ^ ((nl & 7) << 3));
        unsigned int o = ((unsigned int)f2bf(acc1) << 16) | f2bf(acc0);
        *(unsigned int*)(&aggs[0][0] + u16idx) = o;
    }
    __syncthreads();

    // ---- Phase B: waves 0-3, wave = n-tile. A = [agg ; hin_own] @ W2T + b --
    if (wave < 4) {
        const int nt = wave;
        const int m = lane & 15;   // node-in-tile for A; out-dim for B/D
        const int q = lane >> 4;   // quad

        bf16x8 a[4];
        {
            int r0 = (m << 6) | ((q * 8) ^ ((m & 7) << 3));        // dims 8q..
            int r1 = (m << 6) | ((32 + q * 8) ^ ((m & 7) << 3));   // 32+8q..
            a[0] = *(const bf16x8*)(&aggs[0][0] + r0);   // k  0..31 (agg)
            a[1] = *(const bf16x8*)(&aggs[0][0] + r1);   // k 32..63 (agg)
        }
        size_t rowa = (size_t)(nb16 + m) << 6;
        a[2] = *(const bf16x8*)(hin + rowa + q * 8);        // k 64..95 (x)
        a[3] = *(const bf16x8*)(hin + rowa + 32 + q * 8);   // k 96..127 (x)

        bf16x8 bfr[4];
        #pragma unroll
        for (int kk = 0; kk < 4; ++kk)
            bfr[kk] = *(const bf16x8*)(W2T + (size_t)(nt * 16 + m) * 128
                                       + kk * 32 + q * 8);

        float bv = brel[nt * 16 + m];
        f32x4 acc = (f32x4){bv, bv, bv, bv};
        #pragma unroll
        for (int kk = 0; kk < 4; ++kk)
            acc = __builtin_amdgcn_mfma_f32_16x16x32_bf16(a[kk], bfr[kk],
                                                          acc, 0, 0, 0);

        #pragma unroll
        for (int r = 0; r < 4; ++r) {
            int n2 = nb16 + q * 4 + r;           // node (row of D)
            float v = acc[r];
            if (relu) v = fmaxf(v, 0.f);
            int dim = nt * 16 + m;               // out dim (col of D)
            if (hout_f32) hout_f32[(size_t)n2 * 64 + dim] = v;
            else          hout_bf [(size_t)n2 * 64 + dim] = f2bf(v);
        }
    }
}

extern "C" void kernel_launch(void* const* d_in, const int* in_sizes, int n_in,
                              void* d_out, int out_size, void* d_ws, size_t ws_size,
                              hipStream_t stream)
{
    const float* x     = (const float*)d_in[0];
    const int*   ei    = (const int*)d_in[1];   // [2, E] int32
    const float* ew    = (const float*)d_in[2];
    const float* Wrel  = (const float*)d_in[3]; // [5, 64, 64]
    const float* brel  = (const float*)d_in[4]; // [5, 64]
    const float* Wroot = (const float*)d_in[5]; // [5, 64, 64]
    float* out = (float*)d_out;

    const int* src = ei;
    const int* dst = ei + N_EDGES;

    const size_t featb_bytes = (size_t)N_NODES * D * 2;  // 12.8 MB bf16
    char* ws = (char*)d_ws;
    size_t off = 0;
    u16*  hb     = (u16*)(ws + off);  off += featb_bytes;   // ping
    u16*  hb2    = (u16*)(ws + off);  off += featb_bytes;   // pong
    u16*  W2T    = (u16*)(ws + off);  off += (size_t)N_LAYERS * 64 * 128 * 2;
    int*  rowptr = (int*)(ws + off);  off += 400016;
    int*  fcur   = (int*)(ws + off);  off += NX * FB * 4;
    int*  fbase  = (int*)(ws + off);  off += (FB + 1) * 4 + 60;
    int2* edges  = (int2*)(ws + off); off += (size_t)N_EDGES * 8;

    // stag aliases hb+hb2 (8000 cells * 320 * 8B = 20.48MB < 25.6MB): live
    // only bin -> sort, both complete (stream-ordered) before f2bf writes hb.
    u64* stag = (u64*)ws;

    u16* hbuf[2] = {hb, hb2};

    const int cblocks = (N_NODES * D / 4 + 255) / 256;
    const int wblocks = (N_LAYERS * 64 * 128 + 255) / 256;  // 160
    const int lblocks = N_NODES / 16;                // 6250 (16 nodes/block)

    // ---- CSR build (counting sort) + converts ----
    initcur_kernel<<<8, 1024, 0, stream>>>(fcur);
    bin_kernel<<<BIN_BLOCKS, BIN_THREADS, 0, stream>>>(src, dst, ew, fcur, stag);
    fscan_kernel<<<1, 1024, 0, stream>>>(fcur, fbase, rowptr);
    sort_kernel<<<FB, 256, 0, stream>>>(stag, fcur, fbase, rowptr, edges);
    f2bf_kernel<<<cblocks, 256, 0, stream>>>(x, hb);
    wprep_kernel<<<wblocks, 256, 0, stream>>>(Wrel, Wroot, W2T);

    // ---- 5 fused GraphConv layers (ping-pong h buffers) ----
    for (int layer = 0; layer < N_LAYERS; ++layer) {
        int last = (layer == N_LAYERS - 1);
        layer_kernel<<<lblocks, 512, 0, stream>>>(
            hbuf[layer & 1], rowptr, edges,
            W2T + (size_t)layer * 64 * 128,
            brel + (size_t)layer * D,
            last ? nullptr : hbuf[(layer + 1) & 1],
            last ? out : nullptr,
            last ? 0 : 1);
    }
}